// Round 1
// baseline (1224.039 us; speedup 1.0000x reference)
//
#include <hip/hip_runtime.h>
#include <math.h>

#define B_N 131072
#define D_DIM 64
#define P_N 32
#define H_DIM 64
#define EPT 8               // elements per thread
#define TPB 256             // threads per block
#define CHUNKS (B_N / (EPT * TPB))   // 64 blocks per (pair, evaltype)

__device__ __forceinline__ float elu_f(float x) {
    // jax.nn.elu(x) = x>0 ? x : expm1(x). fp32 exp(x)-1: per-element abs err
    // ~6e-8 pseudo-random across B=131072 -> negligible after mean + joint/marg cancel.
    return x > 0.0f ? x : (__expf(x) - 1.0f);
}

// W2 [64][64] row-major -> W2T [k][m] so column k is contiguous (uniform s_load_dwordx16 path)
__global__ void transpose_w2(const float* __restrict__ W2, float* __restrict__ W2T) {
    int t = blockIdx.x * blockDim.x + threadIdx.x; // 4096 threads
    int m = t >> 6, k = t & 63;
    W2T[k * 64 + m] = W2[m * 64 + k];
}

__global__ __launch_bounds__(TPB, 4)
void mine_main(const float* __restrict__ z,
               const float* __restrict__ W1, const float* __restrict__ b1,
               const float* __restrict__ W2T, const float* __restrict__ b2,
               const float* __restrict__ W3, const float* __restrict__ b3,
               const int* __restrict__ pairs, const int* __restrict__ perms,
               double* __restrict__ partials) {
    const int p   = blockIdx.y;
    const int et  = blockIdx.z;           // 0 = joint, 1 = marginal
    const int i   = pairs[2 * p];
    const int j   = pairs[2 * p + 1];
    const int base = blockIdx.x * (EPT * TPB);
    const int tid  = threadIdx.x;

    // Prefetch all inputs for this thread's 8 elements (independent loads, ILP)
    float av[EPT], bv[EPT];
    #pragma unroll
    for (int e = 0; e < EPT; ++e) {
        int b = base + e * TPB + tid;
        bv[e] = z[b * D_DIM + j];
        int bi = (et == 0) ? b : perms[p * B_N + b];
        av[e] = z[bi * D_DIM + i];
    }

    double acc = 0.0;
    for (int e = 0; e < EPT; ++e) {
        const float a  = av[e];
        const float bb = bv[e];
        float h1[H_DIM];
        #pragma unroll
        for (int m = 0; m < H_DIM; ++m)
            h1[m] = elu_f(fmaf(a, W1[m], fmaf(bb, W1[64 + m], b1[m])));

        float score = b3[0];
        #pragma unroll 2
        for (int k = 0; k < H_DIM; ++k) {
            float s2 = b2[k];
            #pragma unroll
            for (int m = 0; m < H_DIM; ++m)
                s2 = fmaf(h1[m], W2T[k * 64 + m], s2);   // uniform -> SGPR operand
            score = fmaf(elu_f(s2), W3[k], score);
        }
        // joint: accumulate score; marg: accumulate exp(score) (libm expf: low-bias,
        // since relative bias of et hits log(et) 1:1)
        acc += (et == 0) ? (double)score : (double)expf(score);
    }

    // deterministic block reduction in fp64
    __shared__ double red[TPB];
    red[tid] = acc;
    __syncthreads();
    for (int s = TPB / 2; s > 0; s >>= 1) {
        if (tid < s) red[tid] += red[tid + s];
        __syncthreads();
    }
    if (tid == 0)
        partials[et * (P_N * CHUNKS) + p * CHUNKS + blockIdx.x] = red[0];
}

__global__ void mine_final(const double* __restrict__ partials, float* __restrict__ out) {
    // single wave of 64; lanes 0..31 own one pair each
    int lane = threadIdx.x;
    double mi = 0.0;
    if (lane < P_N) {
        double sj = 0.0, sm = 0.0;
        for (int c = 0; c < CHUNKS; ++c) {
            sj += partials[lane * CHUNKS + c];
            sm += partials[P_N * CHUNKS + lane * CHUNKS + c];
        }
        mi = sj / (double)B_N - log(sm / (double)B_N);
    }
    #pragma unroll
    for (int off = 32; off > 0; off >>= 1) mi += __shfl_down(mi, off);
    if (lane == 0) out[0] = (float)(mi / (double)P_N);
}

extern "C" void kernel_launch(void* const* d_in, const int* in_sizes, int n_in,
                              void* d_out, int out_size, void* d_ws, size_t ws_size,
                              hipStream_t stream) {
    const float* z     = (const float*)d_in[0];
    const float* W1    = (const float*)d_in[1];
    const float* b1    = (const float*)d_in[2];
    const float* W2    = (const float*)d_in[3];
    const float* b2    = (const float*)d_in[4];
    const float* W3    = (const float*)d_in[5];
    const float* b3    = (const float*)d_in[6];
    const int*   pairs = (const int*)d_in[7];
    const int*   perms = (const int*)d_in[8];

    float*  W2T      = (float*)d_ws;                          // 16 KB
    double* partials = (double*)((char*)d_ws + 16 * 1024);    // 2*32*64 doubles = 32 KB

    transpose_w2<<<16, 256, 0, stream>>>(W2, W2T);
    dim3 grid(CHUNKS, P_N, 2);
    mine_main<<<grid, TPB, 0, stream>>>(z, W1, b1, W2T, b2, W3, b3, pairs, perms, partials);
    mine_final<<<1, 64, 0, stream>>>(partials, (float*)d_out);
}

// Round 2
// 383.812 us; speedup vs baseline: 3.1892x; 3.1892x over previous
//
#include <hip/hip_runtime.h>
#include <hip/hip_bf16.h>
#include <math.h>

#define B_N   131072
#define D_DIM 64
#define P_N   32
#define H_DIM 64
#define TPB   256
#define GRIDX 64
#define SPB   (B_N / GRIDX)      // samples per block = 2048
#define SPI   64                 // samples per block-iter (4 waves * 16)
#define ITERS (SPB / SPI)        // 32

typedef __attribute__((ext_vector_type(8))) short bf16x8;
typedef __attribute__((ext_vector_type(4))) float f32x4;

static __device__ __forceinline__ unsigned short bfbits(float f) {
    __hip_bfloat16 b = __float2bfloat16(f);
    unsigned short u; __builtin_memcpy(&u, &b, 2); return u;
}
static __device__ __forceinline__ float bf2f(unsigned short u) {
    return __uint_as_float(((unsigned)u) << 16);
}
static __device__ __forceinline__ float elu_f(float x) {
    return x > 0.0f ? x : (__expf(x) - 1.0f);
}

// W2 [64][64] -> bf16 hi/lo planes in MFMA B-fragment-ready layout:
// element t = ((c*4 + n)*64 + lane)*8 + m  holds  W2[k][col],
// k = c*32 + (lane>>4)*8 + m, col = n*16 + (lane&15).
__global__ void prep_weights(const float* __restrict__ W2,
                             unsigned short* __restrict__ w2hi,
                             unsigned short* __restrict__ w2lo) {
    int t = blockIdx.x * blockDim.x + threadIdx.x;   // 0..4095
    int m = t & 7, l = (t >> 3) & 63, n = (t >> 9) & 3, c = t >> 11;
    int k = c * 32 + (l >> 4) * 8 + m;
    int col = n * 16 + (l & 15);
    float v = W2[k * 64 + col];
    unsigned short hi = bfbits(v);
    unsigned short lo = bfbits(v - bf2f(hi));
    w2hi[t] = hi;
    w2lo[t] = lo;
}

static __device__ __forceinline__ void epi(f32x4 a, float b2n, float w3n, float sc[4]) {
    #pragma unroll
    for (int r = 0; r < 4; ++r)
        sc[r] = fmaf(elu_f(a[r] + b2n), w3n, sc[r]);
}

__global__ __launch_bounds__(TPB, 2)
void mine_mfma(const float* __restrict__ z,
               const float* __restrict__ W1, const float* __restrict__ b1,
               const unsigned short* __restrict__ w2hi,
               const unsigned short* __restrict__ w2lo,
               const float* __restrict__ b2,
               const float* __restrict__ W3, const float* __restrict__ b3,
               const int* __restrict__ pairs, const int* __restrict__ perms,
               double* __restrict__ partials) {
    const int p    = blockIdx.y;
    const int et   = blockIdx.z;          // 0=joint 1=marg
    const int i    = pairs[2 * p];
    const int j    = pairs[2 * p + 1];
    const int tid  = threadIdx.x;
    const int lane = tid & 63;
    const int wv   = tid >> 6;
    const int g    = lane >> 4;           // k-group
    const int r16  = lane & 15;           // A-row / B-col / D-col index

    // layer-1 weights for this lane's A-frag dims (c*32 + g*8 + m)
    float w1a[2][8], w1b[2][8], b1v[2][8];
    #pragma unroll
    for (int c = 0; c < 2; ++c)
        #pragma unroll
        for (int m = 0; m < 8; ++m) {
            int d = c * 32 + g * 8 + m;
            w1a[c][m] = W1[d];
            w1b[c][m] = W1[64 + d];
            b1v[c][m] = b1[d];
        }

    // W2 fragments (held in VGPRs for the whole kernel)
    const bf16x8* fh = (const bf16x8*)w2hi;
    const bf16x8* fl = (const bf16x8*)w2lo;
    bf16x8 wh[2][4], wl[2][4];
    #pragma unroll
    for (int c = 0; c < 2; ++c)
        #pragma unroll
        for (int n = 0; n < 4; ++n) {
            wh[c][n] = fh[(c * 4 + n) * 64 + lane];
            wl[c][n] = fl[(c * 4 + n) * 64 + lane];
        }

    float b2v[4], w3v[4];
    #pragma unroll
    for (int n = 0; n < 4; ++n) {
        b2v[n] = b2[n * 16 + r16];
        w3v[n] = W3[n * 16 + r16];
    }
    const float b3v = b3[0];

    const int sbase = blockIdx.x * SPB + wv * 16 + r16;

    // software-pipelined input loads (perm gather is a 2-level chain)
    int   s_cur = sbase;
    float bcur  = z[s_cur * 64 + j];
    int   bi    = et ? perms[p * B_N + s_cur] : s_cur;
    float acur  = z[bi * 64 + i];

    double accd = 0.0;

    for (int t = 0; t < ITERS; ++t) {
        const int tn  = (t + 1 < ITERS) ? t + 1 : t;
        const int s_n = sbase + tn * SPI;
        float bnxt = z[s_n * 64 + j];
        int   bin  = et ? perms[p * B_N + s_n] : s_n;
        float anxt = z[bin * 64 + i];

        // layer 1 + hi/lo bf16 split straight into A-frags
        bf16x8 ah[2], al[2];
        #pragma unroll
        for (int c = 0; c < 2; ++c)
            #pragma unroll
            for (int m = 0; m < 8; ++m) {
                float h = elu_f(fmaf(acur, w1a[c][m], fmaf(bcur, w1b[c][m], b1v[c][m])));
                unsigned short hb = bfbits(h);
                unsigned short lb = bfbits(h - bf2f(hb));
                ah[c][m] = (short)hb;
                al[c][m] = (short)lb;
            }

        // layer 2: C[16 samp x 64 kout] via 3-product bf16 split
        f32x4 acc0 = {0.f,0.f,0.f,0.f}, acc1 = {0.f,0.f,0.f,0.f};
        f32x4 acc2 = {0.f,0.f,0.f,0.f}, acc3 = {0.f,0.f,0.f,0.f};
        #pragma unroll
        for (int c = 0; c < 2; ++c) {
            acc0 = __builtin_amdgcn_mfma_f32_16x16x32_bf16(ah[c], wh[c][0], acc0, 0, 0, 0);
            acc1 = __builtin_amdgcn_mfma_f32_16x16x32_bf16(ah[c], wh[c][1], acc1, 0, 0, 0);
            acc2 = __builtin_amdgcn_mfma_f32_16x16x32_bf16(ah[c], wh[c][2], acc2, 0, 0, 0);
            acc3 = __builtin_amdgcn_mfma_f32_16x16x32_bf16(ah[c], wh[c][3], acc3, 0, 0, 0);
            acc0 = __builtin_amdgcn_mfma_f32_16x16x32_bf16(ah[c], wl[c][0], acc0, 0, 0, 0);
            acc1 = __builtin_amdgcn_mfma_f32_16x16x32_bf16(ah[c], wl[c][1], acc1, 0, 0, 0);
            acc2 = __builtin_amdgcn_mfma_f32_16x16x32_bf16(ah[c], wl[c][2], acc2, 0, 0, 0);
            acc3 = __builtin_amdgcn_mfma_f32_16x16x32_bf16(ah[c], wl[c][3], acc3, 0, 0, 0);
            acc0 = __builtin_amdgcn_mfma_f32_16x16x32_bf16(al[c], wh[c][0], acc0, 0, 0, 0);
            acc1 = __builtin_amdgcn_mfma_f32_16x16x32_bf16(al[c], wh[c][1], acc1, 0, 0, 0);
            acc2 = __builtin_amdgcn_mfma_f32_16x16x32_bf16(al[c], wh[c][2], acc2, 0, 0, 0);
            acc3 = __builtin_amdgcn_mfma_f32_16x16x32_bf16(al[c], wh[c][3], acc3, 0, 0, 0);
        }

        // epilogue: +b2, elu, *W3, reduce over 16 lanes (kout), + b3
        float sc[4] = {0.f, 0.f, 0.f, 0.f};
        epi(acc0, b2v[0], w3v[0], sc);
        epi(acc1, b2v[1], w3v[1], sc);
        epi(acc2, b2v[2], w3v[2], sc);
        epi(acc3, b2v[3], w3v[3], sc);

        #pragma unroll
        for (int mask = 1; mask <= 8; mask <<= 1) {
            #pragma unroll
            for (int r = 0; r < 4; ++r)
                sc[r] += __shfl_xor(sc[r], mask, 64);
        }

        if (et == 0) {
            accd += (double)(sc[0] + b3v) + (double)(sc[1] + b3v)
                  + (double)(sc[2] + b3v) + (double)(sc[3] + b3v);
        } else {
            accd += (double)expf(sc[0] + b3v) + (double)expf(sc[1] + b3v)
                  + (double)expf(sc[2] + b3v) + (double)expf(sc[3] + b3v);
        }

        acur = anxt; bcur = bnxt; s_cur = s_n;
    }

    // deterministic fp64 block reduction; each sample was counted 16x (lane redundancy)
    __shared__ double red[TPB];
    red[tid] = accd;
    __syncthreads();
    for (int s = TPB / 2; s > 0; s >>= 1) {
        if (tid < s) red[tid] += red[tid + s];
        __syncthreads();
    }
    if (tid == 0)
        partials[et * (P_N * GRIDX) + p * GRIDX + blockIdx.x] = red[0] * (1.0 / 16.0);
}

__global__ void mine_final(const double* __restrict__ partials, float* __restrict__ out) {
    int lane = threadIdx.x;
    double mi = 0.0;
    if (lane < P_N) {
        double sj = 0.0, sm = 0.0;
        for (int c = 0; c < GRIDX; ++c) {
            sj += partials[lane * GRIDX + c];
            sm += partials[P_N * GRIDX + lane * GRIDX + c];
        }
        mi = sj / (double)B_N - log(sm / (double)B_N);
    }
    #pragma unroll
    for (int off = 32; off > 0; off >>= 1) mi += __shfl_down(mi, off);
    if (lane == 0) out[0] = (float)(mi / (double)P_N);
}

extern "C" void kernel_launch(void* const* d_in, const int* in_sizes, int n_in,
                              void* d_out, int out_size, void* d_ws, size_t ws_size,
                              hipStream_t stream) {
    const float* z     = (const float*)d_in[0];
    const float* W1    = (const float*)d_in[1];
    const float* b1    = (const float*)d_in[2];
    const float* W2    = (const float*)d_in[3];
    const float* b2    = (const float*)d_in[4];
    const float* W3    = (const float*)d_in[5];
    const float* b3    = (const float*)d_in[6];
    const int*   pairs = (const int*)d_in[7];
    const int*   perms = (const int*)d_in[8];

    unsigned short* w2hi = (unsigned short*)d_ws;                    // 8 KB
    unsigned short* w2lo = (unsigned short*)((char*)d_ws + 8192);    // 8 KB
    double* partials     = (double*)((char*)d_ws + 16384);           // 32 KB

    prep_weights<<<16, 256, 0, stream>>>(W2, w2hi, w2lo);
    dim3 grid(GRIDX, P_N, 2);
    mine_mfma<<<grid, TPB, 0, stream>>>(z, W1, b1, w2hi, w2lo, b2, W3, b3,
                                        pairs, perms, partials);
    mine_final<<<1, 64, 0, stream>>>(partials, (float*)d_out);
}

// Round 3
// 375.538 us; speedup vs baseline: 3.2594x; 1.0220x over previous
//
#include <hip/hip_runtime.h>
#include <hip/hip_bf16.h>
#include <math.h>

#define B_N   131072
#define D_DIM 64
#define P_N   32
#define H_DIM 64
#define TPB   256
#define GRIDX 64
#define SPB   (B_N / GRIDX)      // samples per block = 2048
#define SPI   64                 // samples per block-iter (4 waves * 16)
#define ITERS (SPB / SPI)        // 32

typedef __attribute__((ext_vector_type(8))) short bf16x8;
typedef __attribute__((ext_vector_type(4))) float f32x4;

static __device__ __forceinline__ unsigned short bfbits(float f) {
    __hip_bfloat16 b = __float2bfloat16(f);
    unsigned short u; __builtin_memcpy(&u, &b, 2); return u;
}
static __device__ __forceinline__ float bf2f(unsigned short u) {
    return __uint_as_float(((unsigned)u) << 16);
}
static __device__ __forceinline__ float elu_f(float x) {
    return x > 0.0f ? x : (__expf(x) - 1.0f);
}

// W2 [64][64] -> bf16 hi/lo planes in MFMA B-fragment-ready layout:
// element t = ((c*4 + n)*64 + lane)*8 + m  holds  W2[k][col],
// k = c*32 + (lane>>4)*8 + m, col = n*16 + (lane&15).
__global__ void prep_weights(const float* __restrict__ W2,
                             unsigned short* __restrict__ w2hi,
                             unsigned short* __restrict__ w2lo) {
    int t = blockIdx.x * blockDim.x + threadIdx.x;   // 0..4095
    int m = t & 7, l = (t >> 3) & 63, n = (t >> 9) & 3, c = t >> 11;
    int k = c * 32 + (l >> 4) * 8 + m;
    int col = n * 16 + (l & 15);
    float v = W2[k * 64 + col];
    unsigned short hi = bfbits(v);
    unsigned short lo = bfbits(v - bf2f(hi));
    w2hi[t] = hi;
    w2lo[t] = lo;
}

static __device__ __forceinline__ void epi(f32x4 a, float w3n, float sc[4]) {
    #pragma unroll
    for (int r = 0; r < 4; ++r)
        sc[r] = fmaf(elu_f(a[r]), w3n, sc[r]);
}

__global__ __launch_bounds__(TPB, 2)
void mine_mfma(const float* __restrict__ z,
               const float* __restrict__ W1, const float* __restrict__ b1,
               const unsigned short* __restrict__ w2hi,
               const unsigned short* __restrict__ w2lo,
               const float* __restrict__ b2,
               const float* __restrict__ W3,
               const int* __restrict__ pairs, const int* __restrict__ perms,
               double* __restrict__ partials) {
    const int p    = blockIdx.y;
    const int et   = blockIdx.z;          // 0=joint 1=marg
    const int i    = pairs[2 * p];
    const int j    = pairs[2 * p + 1];
    const int tid  = threadIdx.x;
    const int lane = tid & 63;
    const int wv   = tid >> 6;
    const int g    = lane >> 4;           // k-group / D-row-group
    const int r16  = lane & 15;           // A-row / B-col / D-col index

    // layer-1 weights for this lane's A-frag dims (c*32 + g*8 + m)
    float w1a[2][8], w1b[2][8], b1v[2][8];
    #pragma unroll
    for (int c = 0; c < 2; ++c)
        #pragma unroll
        for (int m = 0; m < 8; ++m) {
            int d = c * 32 + g * 8 + m;
            w1a[c][m] = W1[d];
            w1b[c][m] = W1[64 + d];
            b1v[c][m] = b1[d];
        }

    // W2 fragments
    const bf16x8* fh = (const bf16x8*)w2hi;
    const bf16x8* fl = (const bf16x8*)w2lo;
    bf16x8 wh[2][4], wl[2][4];
    #pragma unroll
    for (int c = 0; c < 2; ++c)
        #pragma unroll
        for (int n = 0; n < 4; ++n) {
            wh[c][n] = fh[(c * 4 + n) * 64 + lane];
            wl[c][n] = fl[(c * 4 + n) * 64 + lane];
        }

    float b2v[4], w3v[4];
    #pragma unroll
    for (int n = 0; n < 4; ++n) {
        b2v[n] = b2[n * 16 + r16];
        w3v[n] = W3[n * 16 + r16];
    }

    const int  sbase = blockIdx.x * SPB + wv * 16 + r16;
    const long pbase = (long)p * B_N;

    // ---- software pipeline: perm idx 2+ iters ahead, z-gathers 2 iters ahead ----
    int   s0g = sbase;
    int   s1g = sbase + SPI;
    int   pmA = et ? perms[pbase + s0g] : s0g;     // t=0
    int   pmB = et ? perms[pbase + s1g] : s1g;     // t=1
    float b_0 = z[s0g * 64 + j];
    float a_0 = z[pmA * 64 + i];
    float b_1 = z[s1g * 64 + j];
    float a_1 = z[pmB * 64 + i];
    int   s2c = sbase + ((2 < ITERS) ? 2 : ITERS - 1) * SPI;
    int   pmC = et ? perms[pbase + s2c] : s2c;     // t=2, in flight

    double accd = 0.0;

    for (int t = 0; t < ITERS; ++t) {
        // issue loads for t+2 (gathers) and t+3 (perm idx)
        const int t2 = (t + 2 < ITERS) ? t + 2 : ITERS - 1;
        const int t3 = (t + 3 < ITERS) ? t + 3 : ITERS - 1;
        const int sN2 = sbase + t2 * SPI;
        const int sN3 = sbase + t3 * SPI;
        int   pmD = et ? perms[pbase + sN3] : sN3;
        float b_2 = z[sN2 * 64 + j];
        float a_2 = z[pmC * 64 + i];

        // layer 1 + hi/lo bf16 split straight into A-frags
        bf16x8 ah[2], al[2];
        #pragma unroll
        for (int c = 0; c < 2; ++c)
            #pragma unroll
            for (int m = 0; m < 8; ++m) {
                float h = elu_f(fmaf(a_0, w1a[c][m], fmaf(b_0, w1b[c][m], b1v[c][m])));
                unsigned short hb = bfbits(h);
                unsigned short lb = bfbits(h - bf2f(hb));
                ah[c][m] = (short)hb;
                al[c][m] = (short)lb;
            }

        // layer 2: C[16 samp x 64 kout], b2 folded into the accumulator init
        f32x4 acc0 = {b2v[0], b2v[0], b2v[0], b2v[0]};
        f32x4 acc1 = {b2v[1], b2v[1], b2v[1], b2v[1]};
        f32x4 acc2 = {b2v[2], b2v[2], b2v[2], b2v[2]};
        f32x4 acc3 = {b2v[3], b2v[3], b2v[3], b2v[3]};
        #pragma unroll
        for (int c = 0; c < 2; ++c) {
            acc0 = __builtin_amdgcn_mfma_f32_16x16x32_bf16(ah[c], wh[c][0], acc0, 0, 0, 0);
            acc1 = __builtin_amdgcn_mfma_f32_16x16x32_bf16(ah[c], wh[c][1], acc1, 0, 0, 0);
            acc2 = __builtin_amdgcn_mfma_f32_16x16x32_bf16(ah[c], wh[c][2], acc2, 0, 0, 0);
            acc3 = __builtin_amdgcn_mfma_f32_16x16x32_bf16(ah[c], wh[c][3], acc3, 0, 0, 0);
            acc0 = __builtin_amdgcn_mfma_f32_16x16x32_bf16(ah[c], wl[c][0], acc0, 0, 0, 0);
            acc1 = __builtin_amdgcn_mfma_f32_16x16x32_bf16(ah[c], wl[c][1], acc1, 0, 0, 0);
            acc2 = __builtin_amdgcn_mfma_f32_16x16x32_bf16(ah[c], wl[c][2], acc2, 0, 0, 0);
            acc3 = __builtin_amdgcn_mfma_f32_16x16x32_bf16(ah[c], wl[c][3], acc3, 0, 0, 0);
            acc0 = __builtin_amdgcn_mfma_f32_16x16x32_bf16(al[c], wh[c][0], acc0, 0, 0, 0);
            acc1 = __builtin_amdgcn_mfma_f32_16x16x32_bf16(al[c], wh[c][1], acc1, 0, 0, 0);
            acc2 = __builtin_amdgcn_mfma_f32_16x16x32_bf16(al[c], wh[c][2], acc2, 0, 0, 0);
            acc3 = __builtin_amdgcn_mfma_f32_16x16x32_bf16(al[c], wh[c][3], acc3, 0, 0, 0);
        }

        // epilogue: elu (b2 already in), *W3, partial per-lane
        float sc[4] = {0.f, 0.f, 0.f, 0.f};
        epi(acc0, w3v[0], sc);
        epi(acc1, w3v[1], sc);
        epi(acc2, w3v[2], sc);
        epi(acc3, w3v[3], sc);

        // distributed reduce over the 16 cols: lane ends with ONE sample's full
        // score (D-row = g*4 + (lane&3)), 4x redundancy across lane bits [3:2]
        {
            const bool o1 = lane & 1;
            float k01 = o1 ? sc[1] : sc[0];
            float s01 = o1 ? sc[0] : sc[1];
            float v01 = k01 + __shfl_xor(s01, 1, 64);
            float k23 = o1 ? sc[3] : sc[2];
            float s23 = o1 ? sc[2] : sc[3];
            float v23 = k23 + __shfl_xor(s23, 1, 64);
            const bool o2 = lane & 2;
            float kk = o2 ? v23 : v01;
            float ss = o2 ? v01 : v23;
            float v  = kk + __shfl_xor(ss, 2, 64);
            v += __shfl_xor(v, 4, 64);
            v += __shfl_xor(v, 8, 64);
            // b3 omitted: cancels exactly in mean(joint) - log(mean(exp(marg)))
            accd += et ? (double)expf(v) : (double)v;
        }

        a_0 = a_1; b_0 = b_1; a_1 = a_2; b_1 = b_2; pmC = pmD;
    }

    // deterministic fp64 block reduction; each sample counted 4x
    __shared__ double red[TPB];
    red[tid] = accd;
    __syncthreads();
    for (int s = TPB / 2; s > 0; s >>= 1) {
        if (tid < s) red[tid] += red[tid + s];
        __syncthreads();
    }
    if (tid == 0)
        partials[et * (P_N * GRIDX) + p * GRIDX + blockIdx.x] = red[0] * 0.25;
}

__global__ void mine_final(const double* __restrict__ partials, float* __restrict__ out) {
    int lane = threadIdx.x;
    double mi = 0.0;
    if (lane < P_N) {
        double sj = 0.0, sm = 0.0;
        for (int c = 0; c < GRIDX; ++c) {
            sj += partials[lane * GRIDX + c];
            sm += partials[P_N * GRIDX + lane * GRIDX + c];
        }
        mi = sj / (double)B_N - log(sm / (double)B_N);
    }
    #pragma unroll
    for (int off = 32; off > 0; off >>= 1) mi += __shfl_down(mi, off);
    if (lane == 0) out[0] = (float)(mi / (double)P_N);
}

extern "C" void kernel_launch(void* const* d_in, const int* in_sizes, int n_in,
                              void* d_out, int out_size, void* d_ws, size_t ws_size,
                              hipStream_t stream) {
    const float* z     = (const float*)d_in[0];
    const float* W1    = (const float*)d_in[1];
    const float* b1    = (const float*)d_in[2];
    const float* W2    = (const float*)d_in[3];
    const float* b2    = (const float*)d_in[4];
    const float* W3    = (const float*)d_in[5];
    const int*   pairs = (const int*)d_in[7];
    const int*   perms = (const int*)d_in[8];

    unsigned short* w2hi = (unsigned short*)d_ws;                    // 8 KB
    unsigned short* w2lo = (unsigned short*)((char*)d_ws + 8192);    // 8 KB
    double* partials     = (double*)((char*)d_ws + 16384);           // 32 KB

    prep_weights<<<16, 256, 0, stream>>>(W2, w2hi, w2lo);
    dim3 grid(GRIDX, P_N, 2);
    mine_mfma<<<grid, TPB, 0, stream>>>(z, W1, b1, w2hi, w2lo, b2, W3,
                                        pairs, perms, partials);
    mine_final<<<1, 64, 0, stream>>>(partials, (float*)d_out);
}

// Round 4
// 362.267 us; speedup vs baseline: 3.3788x; 1.0366x over previous
//
#include <hip/hip_runtime.h>
#include <hip/hip_bf16.h>
#include <math.h>

#define B_N   131072
#define D_DIM 64
#define P_N   32
#define H_DIM 64
#define TPB   256
#define GRIDX 64
#define SPB   (B_N / GRIDX)      // samples per block = 2048
#define SPI   64                 // samples per block-iter (4 waves * 16)
#define ITERS (SPB / SPI)        // 32

#define K_L2E 1.44269504088896340736f   // log2(e)
#define LN2F  0.693147180559945309f     // 1/K

typedef __attribute__((ext_vector_type(8))) short bf16x8;
typedef __attribute__((ext_vector_type(4))) float f32x4;

static __device__ __forceinline__ unsigned short bfbits(float f) {
    __hip_bfloat16 b = __float2bfloat16(f);
    unsigned short u; __builtin_memcpy(&u, &b, 2); return u;
}
static __device__ __forceinline__ float bf2f(unsigned short u) {
    return __uint_as_float(((unsigned)u) << 16);
}

// W2 [64][64] -> bf16 hi/lo planes in MFMA B-fragment-ready layout:
// element t = ((c*4 + n)*64 + lane)*8 + m  holds  W2[k][col],
// k = c*32 + (lane>>4)*8 + m, col = n*16 + (lane&15).
__global__ void prep_weights(const float* __restrict__ W2,
                             unsigned short* __restrict__ w2hi,
                             unsigned short* __restrict__ w2lo) {
    int t = blockIdx.x * blockDim.x + threadIdx.x;   // 0..4095
    int m = t & 7, l = (t >> 3) & 63, n = (t >> 9) & 3, c = t >> 11;
    int k = c * 32 + (l >> 4) * 8 + m;
    int col = n * 16 + (l & 15);
    float v = W2[k * 64 + col];
    unsigned short hi = bfbits(v);
    unsigned short lo = bfbits(v - bf2f(hi));
    w2hi[t] = hi;
    w2lo[t] = lo;
}

// K-folded elu: input is K*x; returns K*elu(x).
// exp2 is the native v_exp_f32; fma(e,K,-K) = K*(e-1).
static __device__ __forceinline__ float eluK(float xk) {
    float e = __builtin_amdgcn_exp2f(xk);
    float neg = fmaf(e, K_L2E, -K_L2E);
    return xk > 0.0f ? xk : neg;
}

__global__ __launch_bounds__(TPB, 2)
void mine_mfma(const float* __restrict__ z,
               const float* __restrict__ W1, const float* __restrict__ b1,
               const unsigned short* __restrict__ w2hi,
               const unsigned short* __restrict__ w2lo,
               const float* __restrict__ b2,
               const float* __restrict__ W3,
               const int* __restrict__ pairs, const int* __restrict__ perms,
               double* __restrict__ partials) {
    const int p    = blockIdx.y;
    const int et   = blockIdx.z;          // 0=joint 1=marg
    const int i    = pairs[2 * p];
    const int j    = pairs[2 * p + 1];
    const int tid  = threadIdx.x;
    const int lane = tid & 63;
    const int wv   = tid >> 6;
    const int g    = lane >> 4;           // k-group
    const int r16  = lane & 15;           // A-row / B-col / D-col index

    // layer-1 weights for this lane's A-frag dims, pre-scaled by K = log2(e)
    float w1a[2][8], w1b[2][8], b1v[2][8];
    #pragma unroll
    for (int c = 0; c < 2; ++c)
        #pragma unroll
        for (int m = 0; m < 8; ++m) {
            int d = c * 32 + g * 8 + m;
            w1a[c][m] = W1[d]      * K_L2E;
            w1b[c][m] = W1[64 + d] * K_L2E;
            b1v[c][m] = b1[d]      * K_L2E;
        }

    // W2 fragments (unchanged; K-scaling carried by h1' = K*h1)
    const bf16x8* fh = (const bf16x8*)w2hi;
    const bf16x8* fl = (const bf16x8*)w2lo;
    bf16x8 wh[2][4], wl[2][4];
    #pragma unroll
    for (int c = 0; c < 2; ++c)
        #pragma unroll
        for (int n = 0; n < 4; ++n) {
            wh[c][n] = fh[(c * 4 + n) * 64 + lane];
            wl[c][n] = fl[(c * 4 + n) * 64 + lane];
        }

    float b2v[4], w3v[4];
    #pragma unroll
    for (int n = 0; n < 4; ++n) {
        b2v[n] = b2[n * 16 + r16] * K_L2E;   // acc' = K*(h1.W2 + b2)
        w3v[n] = W3[n * 16 + r16] * LN2F;    // score = h2' * (W3/K)
    }

    const int  sbase = blockIdx.x * SPB + wv * 16 + r16;
    const long pbase = (long)p * B_N;

    // ---- software pipeline: perm idx 3 iters ahead, z-gathers 2 iters ahead ----
    int   s0g = sbase;
    int   s1g = sbase + SPI;
    int   pmA = et ? perms[pbase + s0g] : s0g;     // t=0
    int   pmB = et ? perms[pbase + s1g] : s1g;     // t=1
    float b_0 = z[s0g * 64 + j];
    float a_0 = z[pmA * 64 + i];
    float b_1 = z[s1g * 64 + j];
    float a_1 = z[pmB * 64 + i];
    int   s2c = sbase + ((2 < ITERS) ? 2 : ITERS - 1) * SPI;
    int   pmC = et ? perms[pbase + s2c] : s2c;     // t=2, in flight

    double accd = 0.0;

    for (int t = 0; t < ITERS; ++t) {
        // issue loads for t+2 (gathers) and t+3 (perm idx)
        const int t2 = (t + 2 < ITERS) ? t + 2 : ITERS - 1;
        const int t3 = (t + 3 < ITERS) ? t + 3 : ITERS - 1;
        const int sN2 = sbase + t2 * SPI;
        const int sN3 = sbase + t3 * SPI;
        int   pmD = et ? perms[pbase + sN3] : sN3;
        float b_2 = z[sN2 * 64 + j];
        float a_2 = z[pmC * 64 + i];

        // layer 1 (K-scaled) + truncation hi/lo bf16 split, v_perm-packed
        union frag { unsigned int u[4]; bf16x8 v; };
        frag ah[2], al[2];
        #pragma unroll
        for (int c = 0; c < 2; ++c)
            #pragma unroll
            for (int w = 0; w < 4; ++w) {
                float pe = fmaf(a_0, w1a[c][2*w],   fmaf(b_0, w1b[c][2*w],   b1v[c][2*w]));
                float po = fmaf(a_0, w1a[c][2*w+1], fmaf(b_0, w1b[c][2*w+1], b1v[c][2*w+1]));
                float he = eluK(pe);
                float ho = eluK(po);
                unsigned ue = __float_as_uint(he), uo = __float_as_uint(ho);
                // hi plane: top 16 bits of each (truncation split)
                ah[c].u[w] = __builtin_amdgcn_perm(uo, ue, 0x07060302u);
                // lo plane: exact residual, truncated to bf16
                float le = he - __uint_as_float(ue & 0xFFFF0000u);
                float lf = ho - __uint_as_float(uo & 0xFFFF0000u);
                al[c].u[w] = __builtin_amdgcn_perm(__float_as_uint(lf),
                                                   __float_as_uint(le), 0x07060302u);
            }

        // layer 2: C[16 samp x 64 kout], K*b2 folded into the accumulator init
        f32x4 acc0 = {b2v[0], b2v[0], b2v[0], b2v[0]};
        f32x4 acc1 = {b2v[1], b2v[1], b2v[1], b2v[1]};
        f32x4 acc2 = {b2v[2], b2v[2], b2v[2], b2v[2]};
        f32x4 acc3 = {b2v[3], b2v[3], b2v[3], b2v[3]};
        #pragma unroll
        for (int c = 0; c < 2; ++c) {
            acc0 = __builtin_amdgcn_mfma_f32_16x16x32_bf16(ah[c].v, wh[c][0], acc0, 0, 0, 0);
            acc1 = __builtin_amdgcn_mfma_f32_16x16x32_bf16(ah[c].v, wh[c][1], acc1, 0, 0, 0);
            acc2 = __builtin_amdgcn_mfma_f32_16x16x32_bf16(ah[c].v, wh[c][2], acc2, 0, 0, 0);
            acc3 = __builtin_amdgcn_mfma_f32_16x16x32_bf16(ah[c].v, wh[c][3], acc3, 0, 0, 0);
            acc0 = __builtin_amdgcn_mfma_f32_16x16x32_bf16(ah[c].v, wl[c][0], acc0, 0, 0, 0);
            acc1 = __builtin_amdgcn_mfma_f32_16x16x32_bf16(ah[c].v, wl[c][1], acc1, 0, 0, 0);
            acc2 = __builtin_amdgcn_mfma_f32_16x16x32_bf16(ah[c].v, wl[c][2], acc2, 0, 0, 0);
            acc3 = __builtin_amdgcn_mfma_f32_16x16x32_bf16(ah[c].v, wl[c][3], acc3, 0, 0, 0);
            acc0 = __builtin_amdgcn_mfma_f32_16x16x32_bf16(al[c].v, wh[c][0], acc0, 0, 0, 0);
            acc1 = __builtin_amdgcn_mfma_f32_16x16x32_bf16(al[c].v, wh[c][1], acc1, 0, 0, 0);
            acc2 = __builtin_amdgcn_mfma_f32_16x16x32_bf16(al[c].v, wh[c][2], acc2, 0, 0, 0);
            acc3 = __builtin_amdgcn_mfma_f32_16x16x32_bf16(al[c].v, wh[c][3], acc3, 0, 0, 0);
        }

        // epilogue: K-folded elu (b2 already in), * (W3*ln2)
        float sc[4] = {0.f, 0.f, 0.f, 0.f};
        #pragma unroll
        for (int r = 0; r < 4; ++r) {
            sc[r] = fmaf(eluK(acc0[r]), w3v[0], sc[r]);
            sc[r] = fmaf(eluK(acc1[r]), w3v[1], sc[r]);
            sc[r] = fmaf(eluK(acc2[r]), w3v[2], sc[r]);
            sc[r] = fmaf(eluK(acc3[r]), w3v[3], sc[r]);
        }

        // distributed reduce over the 16 cols: lane ends with ONE sample's full
        // score (D-row = g*4 + (lane&3)), 4x redundancy across lane bits [3:2]
        {
            const bool o1 = lane & 1;
            float k01 = o1 ? sc[1] : sc[0];
            float s01 = o1 ? sc[0] : sc[1];
            float v01 = k01 + __shfl_xor(s01, 1, 64);
            float k23 = o1 ? sc[3] : sc[2];
            float s23 = o1 ? sc[2] : sc[3];
            float v23 = k23 + __shfl_xor(s23, 1, 64);
            const bool o2 = lane & 2;
            float kk = o2 ? v23 : v01;
            float ss = o2 ? v01 : v23;
            float v  = kk + __shfl_xor(ss, 2, 64);
            v += __shfl_xor(v, 4, 64);
            v += __shfl_xor(v, 8, 64);
            // b3 omitted: cancels exactly in mean(joint) - log(mean(exp(marg)))
            accd += et ? (double)expf(v) : (double)v;
        }

        a_0 = a_1; b_0 = b_1; a_1 = a_2; b_1 = b_2; pmC = pmD;
    }

    // deterministic fp64 block reduction; each sample counted 4x
    __shared__ double red[TPB];
    red[tid] = accd;
    __syncthreads();
    for (int s = TPB / 2; s > 0; s >>= 1) {
        if (tid < s) red[tid] += red[tid + s];
        __syncthreads();
    }
    if (tid == 0)
        partials[et * (P_N * GRIDX) + p * GRIDX + blockIdx.x] = red[0] * 0.25;
}

__global__ void mine_final(const double* __restrict__ partials, float* __restrict__ out) {
    int lane = threadIdx.x;
    double mi = 0.0;
    if (lane < P_N) {
        double sj = 0.0, sm = 0.0;
        for (int c = 0; c < GRIDX; ++c) {
            sj += partials[lane * GRIDX + c];
            sm += partials[P_N * GRIDX + lane * GRIDX + c];
        }
        mi = sj / (double)B_N - log(sm / (double)B_N);
    }
    #pragma unroll
    for (int off = 32; off > 0; off >>= 1) mi += __shfl_down(mi, off);
    if (lane == 0) out[0] = (float)(mi / (double)P_N);
}

extern "C" void kernel_launch(void* const* d_in, const int* in_sizes, int n_in,
                              void* d_out, int out_size, void* d_ws, size_t ws_size,
                              hipStream_t stream) {
    const float* z     = (const float*)d_in[0];
    const float* W1    = (const float*)d_in[1];
    const float* b1    = (const float*)d_in[2];
    const float* W2    = (const float*)d_in[3];
    const float* b2    = (const float*)d_in[4];
    const float* W3    = (const float*)d_in[5];
    const int*   pairs = (const int*)d_in[7];
    const int*   perms = (const int*)d_in[8];

    unsigned short* w2hi = (unsigned short*)d_ws;                    // 8 KB
    unsigned short* w2lo = (unsigned short*)((char*)d_ws + 8192);    // 8 KB
    double* partials     = (double*)((char*)d_ws + 16384);           // 32 KB

    prep_weights<<<16, 256, 0, stream>>>(W2, w2hi, w2lo);
    dim3 grid(GRIDX, P_N, 2);
    mine_mfma<<<grid, TPB, 0, stream>>>(z, W1, b1, w2hi, w2lo, b2, W3,
                                        pairs, perms, partials);
    mine_final<<<1, 64, 0, stream>>>(partials, (float*)d_out);
}

// Round 5
// 360.996 us; speedup vs baseline: 3.3907x; 1.0035x over previous
//
#include <hip/hip_runtime.h>
#include <hip/hip_bf16.h>
#include <math.h>

#define B_N   131072
#define D_DIM 64
#define P_N   32
#define H_DIM 64
#define TPB   256
#define GRIDX 64
#define SPB   (B_N / GRIDX)      // samples per block = 2048
#define SPI   64                 // samples per block-iter (4 waves * 16)
#define ITERS (SPB / SPI)        // 32

#define K_L2E 1.44269504088896340736f   // log2(e)
#define LN2F  0.693147180559945309f     // 1/K

typedef __attribute__((ext_vector_type(8))) short bf16x8;
typedef __attribute__((ext_vector_type(4))) float f32x4;

#define PIN(x) asm volatile("" : "+v"(x))

static __device__ __forceinline__ unsigned short bfbits(float f) {
    __hip_bfloat16 b = __float2bfloat16(f);
    unsigned short u; __builtin_memcpy(&u, &b, 2); return u;
}
static __device__ __forceinline__ float bf2f(unsigned short u) {
    return __uint_as_float(((unsigned)u) << 16);
}

// W2 [64][64] -> bf16 hi/lo planes in MFMA B-fragment-ready layout:
// element t = ((c*4 + n)*64 + lane)*8 + m  holds  W2[k][col],
// k = c*32 + (lane>>4)*8 + m, col = n*16 + (lane&15).
__global__ void prep_weights(const float* __restrict__ W2,
                             unsigned short* __restrict__ w2hi,
                             unsigned short* __restrict__ w2lo) {
    int t = blockIdx.x * blockDim.x + threadIdx.x;   // 0..4095
    int m = t & 7, l = (t >> 3) & 63, n = (t >> 9) & 3, c = t >> 11;
    int k = c * 32 + (l >> 4) * 8 + m;
    int col = n * 16 + (l & 15);
    float v = W2[k * 64 + col];
    unsigned short hi = bfbits(v);
    unsigned short lo = bfbits(v - bf2f(hi));
    w2hi[t] = hi;
    w2lo[t] = lo;
}

// K-folded elu: input is K*x; returns K*elu(x).
static __device__ __forceinline__ float eluK(float xk) {
    float e = __builtin_amdgcn_exp2f(xk);
    float neg = fmaf(e, K_L2E, -K_L2E);
    return xk > 0.0f ? xk : neg;
}

union Frag { unsigned u[4]; bf16x8 v; };

template<int ET>
__global__ __launch_bounds__(TPB, 3)
void mine_mfma(const float* __restrict__ z,
               const float* __restrict__ W1, const float* __restrict__ b1,
               const unsigned short* __restrict__ w2hi,
               const unsigned short* __restrict__ w2lo,
               const float* __restrict__ b2,
               const float* __restrict__ W3,
               const int* __restrict__ pairs, const int* __restrict__ perms,
               double* __restrict__ partials) {
    const int p    = blockIdx.y;
    const int i    = pairs[2 * p];
    const int j    = pairs[2 * p + 1];
    const int tid  = threadIdx.x;
    const int lane = tid & 63;
    const int wv   = tid >> 6;
    const int g    = lane >> 4;           // k-group
    const int r16  = lane & 15;           // A-row / B-col / D-col index

    // layer-1 weights for this lane's A-frag dims, pre-scaled by K = log2(e)
    float w1a[2][8], w1b[2][8], b1v[2][8];
    #pragma unroll
    for (int c = 0; c < 2; ++c)
        #pragma unroll
        for (int m = 0; m < 8; ++m) {
            int d = c * 32 + g * 8 + m;
            w1a[c][m] = W1[d]      * K_L2E;
            w1b[c][m] = W1[64 + d] * K_L2E;
            b1v[c][m] = b1[d]      * K_L2E;
        }

    // W2 fragments
    const bf16x8* fh = (const bf16x8*)w2hi;
    const bf16x8* fl = (const bf16x8*)w2lo;
    Frag wh[2][4], wl[2][4];
    #pragma unroll
    for (int c = 0; c < 2; ++c)
        #pragma unroll
        for (int n = 0; n < 4; ++n) {
            wh[c][n].v = fh[(c * 4 + n) * 64 + lane];
            wl[c][n].v = fl[(c * 4 + n) * 64 + lane];
        }

    float b2v[4], w3v[4];
    #pragma unroll
    for (int n = 0; n < 4; ++n) {
        b2v[n] = b2[n * 16 + r16] * K_L2E;   // acc' = K*(h1.W2 + b2)
        w3v[n] = W3[n * 16 + r16] * LN2F;    // score = h2' * (W3/K)
    }

    // ---- pin all loop-invariant weights into VGPRs (forbid rematerialization) ----
    #pragma unroll
    for (int c = 0; c < 2; ++c)
        #pragma unroll
        for (int m = 0; m < 8; ++m) {
            PIN(w1a[c][m]); PIN(w1b[c][m]); PIN(b1v[c][m]);
        }
    #pragma unroll
    for (int c = 0; c < 2; ++c)
        #pragma unroll
        for (int n = 0; n < 4; ++n)
            #pragma unroll
            for (int q = 0; q < 4; ++q) {
                PIN(wh[c][n].u[q]); PIN(wl[c][n].u[q]);
            }

    const int  sbase = blockIdx.x * SPB + wv * 16 + r16;
    const long pbase = (long)p * B_N;

    // ---- software pipeline (depth 2; perm idx one extra step ahead) ----
    float a_0, b_0, a_1, b_1;
    int pm1 = 0;
    {
        const int s0 = sbase;
        const int s1 = sbase + SPI;
        int pm0 = ET ? perms[pbase + s0] : s0;
        b_0 = z[s0 * 64 + j];
        a_0 = z[pm0 * 64 + i];
        pm1 = ET ? perms[pbase + s1] : s1;
        b_1 = z[s1 * 64 + j];
        a_1 = z[pm1 * 64 + i];
    }

    double accd = 0.0;

    for (int t = 0; t < ITERS; ++t) {
        // prefetch inputs for t+2
        const int t2  = (t + 2 < ITERS) ? t + 2 : ITERS - 1;
        const int sN2 = sbase + t2 * SPI;
        int   pm2 = ET ? perms[pbase + sN2] : sN2;
        float b_2 = z[sN2 * 64 + j];
        float a_2 = z[pm2 * 64 + i];

        // layer 1 (K-scaled) + truncation hi/lo bf16 split, v_perm-packed
        Frag ah[2], al[2];
        #pragma unroll
        for (int c = 0; c < 2; ++c)
            #pragma unroll
            for (int w = 0; w < 4; ++w) {
                float pe = fmaf(a_0, w1a[c][2*w],   fmaf(b_0, w1b[c][2*w],   b1v[c][2*w]));
                float po = fmaf(a_0, w1a[c][2*w+1], fmaf(b_0, w1b[c][2*w+1], b1v[c][2*w+1]));
                float he = eluK(pe);
                float ho = eluK(po);
                unsigned ue = __float_as_uint(he), uo = __float_as_uint(ho);
                ah[c].u[w] = __builtin_amdgcn_perm(uo, ue, 0x07060302u);
                float le = he - __uint_as_float(ue & 0xFFFF0000u);
                float lf = ho - __uint_as_float(uo & 0xFFFF0000u);
                al[c].u[w] = __builtin_amdgcn_perm(__float_as_uint(lf),
                                                   __float_as_uint(le), 0x07060302u);
            }

        // layer 2: C[16 samp x 64 kout], K*b2 folded into the accumulator init
        f32x4 acc0 = {b2v[0], b2v[0], b2v[0], b2v[0]};
        f32x4 acc1 = {b2v[1], b2v[1], b2v[1], b2v[1]};
        f32x4 acc2 = {b2v[2], b2v[2], b2v[2], b2v[2]};
        f32x4 acc3 = {b2v[3], b2v[3], b2v[3], b2v[3]};
        #pragma unroll
        for (int c = 0; c < 2; ++c) {
            acc0 = __builtin_amdgcn_mfma_f32_16x16x32_bf16(ah[c].v, wh[c][0].v, acc0, 0, 0, 0);
            acc1 = __builtin_amdgcn_mfma_f32_16x16x32_bf16(ah[c].v, wh[c][1].v, acc1, 0, 0, 0);
            acc2 = __builtin_amdgcn_mfma_f32_16x16x32_bf16(ah[c].v, wh[c][2].v, acc2, 0, 0, 0);
            acc3 = __builtin_amdgcn_mfma_f32_16x16x32_bf16(ah[c].v, wh[c][3].v, acc3, 0, 0, 0);
            acc0 = __builtin_amdgcn_mfma_f32_16x16x32_bf16(ah[c].v, wl[c][0].v, acc0, 0, 0, 0);
            acc1 = __builtin_amdgcn_mfma_f32_16x16x32_bf16(ah[c].v, wl[c][1].v, acc1, 0, 0, 0);
            acc2 = __builtin_amdgcn_mfma_f32_16x16x32_bf16(ah[c].v, wl[c][2].v, acc2, 0, 0, 0);
            acc3 = __builtin_amdgcn_mfma_f32_16x16x32_bf16(ah[c].v, wl[c][3].v, acc3, 0, 0, 0);
            acc0 = __builtin_amdgcn_mfma_f32_16x16x32_bf16(al[c].v, wh[c][0].v, acc0, 0, 0, 0);
            acc1 = __builtin_amdgcn_mfma_f32_16x16x32_bf16(al[c].v, wh[c][1].v, acc1, 0, 0, 0);
            acc2 = __builtin_amdgcn_mfma_f32_16x16x32_bf16(al[c].v, wh[c][2].v, acc2, 0, 0, 0);
            acc3 = __builtin_amdgcn_mfma_f32_16x16x32_bf16(al[c].v, wh[c][3].v, acc3, 0, 0, 0);
        }

        // epilogue: K-folded elu (b2 already in), * (W3*ln2)
        float sc[4] = {0.f, 0.f, 0.f, 0.f};
        #pragma unroll
        for (int r = 0; r < 4; ++r) {
            sc[r] = fmaf(eluK(acc0[r]), w3v[0], sc[r]);
            sc[r] = fmaf(eluK(acc1[r]), w3v[1], sc[r]);
            sc[r] = fmaf(eluK(acc2[r]), w3v[2], sc[r]);
            sc[r] = fmaf(eluK(acc3[r]), w3v[3], sc[r]);
        }

        if (ET == 0) {
            // joint: scores are linear -> defer everything to the fp64 block
            // reduce. Each lane's sc values are distinct D elements (no
            // redundancy): sum directly.
            accd += (double)((sc[0] + sc[1]) + (sc[2] + sc[3]));
        } else {
            // marg: need full per-sample score before exp. Distributed reduce
            // over the 16 cols; lane ends with one sample's score (4x redundant).
            const bool o1 = lane & 1;
            float k01 = o1 ? sc[1] : sc[0];
            float s01 = o1 ? sc[0] : sc[1];
            float v01 = k01 + __shfl_xor(s01, 1, 64);
            float k23 = o1 ? sc[3] : sc[2];
            float s23 = o1 ? sc[2] : sc[3];
            float v23 = k23 + __shfl_xor(s23, 1, 64);
            const bool o2 = lane & 2;
            float kk = o2 ? v23 : v01;
            float ss = o2 ? v01 : v23;
            float v  = kk + __shfl_xor(ss, 2, 64);
            v += __shfl_xor(v, 4, 64);
            v += __shfl_xor(v, 8, 64);
            // b3 omitted: cancels exactly in mean(joint) - log(mean(exp(marg)))
            accd += (double)expf(v);
        }

        a_0 = a_1; b_0 = b_1; a_1 = a_2; b_1 = b_2;
    }

    // deterministic fp64 block reduction
    __shared__ double red[TPB];
    red[tid] = accd;
    __syncthreads();
    for (int s = TPB / 2; s > 0; s >>= 1) {
        if (tid < s) red[tid] += red[tid + s];
        __syncthreads();
    }
    if (tid == 0) {
        double v = (ET == 0) ? red[0] : red[0] * 0.25;   // marg counted 4x
        partials[ET * (P_N * GRIDX) + p * GRIDX + blockIdx.x] = v;
    }
}

__global__ void mine_final(const double* __restrict__ partials, float* __restrict__ out) {
    int lane = threadIdx.x;
    double mi = 0.0;
    if (lane < P_N) {
        double sj = 0.0, sm = 0.0;
        for (int c = 0; c < GRIDX; ++c) {
            sj += partials[lane * GRIDX + c];
            sm += partials[P_N * GRIDX + lane * GRIDX + c];
        }
        mi = sj / (double)B_N - log(sm / (double)B_N);
    }
    #pragma unroll
    for (int off = 32; off > 0; off >>= 1) mi += __shfl_down(mi, off);
    if (lane == 0) out[0] = (float)(mi / (double)P_N);
}

extern "C" void kernel_launch(void* const* d_in, const int* in_sizes, int n_in,
                              void* d_out, int out_size, void* d_ws, size_t ws_size,
                              hipStream_t stream) {
    const float* z     = (const float*)d_in[0];
    const float* W1    = (const float*)d_in[1];
    const float* b1    = (const float*)d_in[2];
    const float* W2    = (const float*)d_in[3];
    const float* b2    = (const float*)d_in[4];
    const float* W3    = (const float*)d_in[5];
    const int*   pairs = (const int*)d_in[7];
    const int*   perms = (const int*)d_in[8];

    unsigned short* w2hi = (unsigned short*)d_ws;                    // 8 KB
    unsigned short* w2lo = (unsigned short*)((char*)d_ws + 8192);    // 8 KB
    double* partials     = (double*)((char*)d_ws + 16384);           // 32 KB

    prep_weights<<<16, 256, 0, stream>>>(W2, w2hi, w2lo);
    dim3 grid(GRIDX, P_N, 1);
    mine_mfma<0><<<grid, TPB, 0, stream>>>(z, W1, b1, w2hi, w2lo, b2, W3,
                                           pairs, perms, partials);
    mine_mfma<1><<<grid, TPB, 0, stream>>>(z, W1, b1, w2hi, w2lo, b2, W3,
                                           pairs, perms, partials);
    mine_final<<<1, 64, 0, stream>>>(partials, (float*)d_out);
}